// Round 12
// baseline (169.303 us; speedup 1.0000x reference)
//
#include <hip/hip_runtime.h>
#include <hip/hip_bf16.h>
#include <cstddef>

// ---------------- problem constants ----------------
#define BB   8
#define HH   120
#define WW   160
#define HW   19200          // HH*WW
#define NPIX 153600         // BB*HW
#define CORC 196

#define AS_  ((float)(6.0/127.0))   // ACT_SCALE
#define FS_  0.03125f               // FLOW_SCALE = 3.96875/127 = 2^-5 exactly

// ws layout:
//   float[0]=sd, float[1]=sp, float[2]=s_c1
//   ushort[32 .. 32+21504)      : convc1 B-frags (bf16 int codes)
//   float[OFF_WF1 .. +128)      : Wf1 dequant
//   float[OFF_WF2 .. +2048)     : Wf2 dequant transposed
//   float[OFF_WD  .. +1152)     : Wd integer codes
//   ushort[OFF_WPQ_US .. +10240): Wp B-frags (bf16 int codes)
#define OFF_WF1 18832
#define OFF_WF2 18960
#define OFF_WD  21008
#define OFF_WPQ_US 44320
#define CFQ_BYTE_OFF 131072         // int8 activation buffer, 8*128*19200 bytes

typedef __attribute__((ext_vector_type(8)))  short short8;
typedef __attribute__((ext_vector_type(4)))  float f32x4;
typedef unsigned int u32;

__device__ __forceinline__ float clip127(float x) {
    return fminf(fmaxf(x, -127.f), 127.f);
}

// round-to-nearest-even fp32 -> bf16 (finite inputs only)
__device__ __forceinline__ unsigned short f2bf(float x) {
    unsigned int u = __float_as_uint(x);
    unsigned int r = (u + 0x7fffu + ((u >> 16) & 1u)) >> 16;
    return (unsigned short)r;
}

// ---------------- kernel 0: weight fake-quant ----------------
__global__ __launch_bounds__(256) void quant_weights(
    const float* __restrict__ Wc1, const float* __restrict__ Wf1,
    const float* __restrict__ Wf2, const float* __restrict__ Wd,
    const float* __restrict__ Wp,  float* __restrict__ ws)
{
    __shared__ float red[256];
    const int t = blockIdx.x;
    const float* src = (t == 0) ? Wc1 : (t == 1) ? Wf1 : (t == 2) ? Wf2 : (t == 3) ? Wd : Wp;
    const int n = (t == 0) ? 18816 : (t == 1) ? 128 : (t == 2) ? 2048 : (t == 3) ? 1152 : 10240;
    const int tid = threadIdx.x;

    float m = 0.f;
    for (int i = tid; i < n; i += 256) m = fmaxf(m, fabsf(src[i]));
    red[tid] = m;
    __syncthreads();
    for (int s = 128; s > 0; s >>= 1) {
        if (tid < s) red[tid] = fmaxf(red[tid], red[tid + s]);
        __syncthreads();
    }
    const float s = red[0] / 127.0f + 1e-12f;

    if (t == 0) {
        // convc1 weights as MFMA B-frags: o = nt*16+(l&15), k = kt*32+((l>>4)<<3)+e
        unsigned short* bf = (unsigned short*)ws + 32;
        for (int j = tid; j < 21504; j += 256) {
            const int e    = j & 7;
            const int l    = (j >> 3) & 63;
            const int tile = j >> 9;
            const int nt   = tile % 6;
            const int kt   = tile / 6;
            const int out  = nt * 16 + (l & 15);
            const int k    = kt * 32 + ((l >> 4) << 3) + e;
            float q = 0.f;
            if (k < 196) q = clip127(rintf(Wc1[out * 196 + k] / s));
            bf[j] = f2bf(q);
        }
        if (tid == 0) ws[2] = s;
    } else if (t == 4) {
        // pointwise weights as MFMA B-frags: 5 n-tiles x 4 k-steps
        unsigned short* bf = (unsigned short*)ws + OFF_WPQ_US;
        for (int j = tid; j < 10240; j += 256) {
            const int e    = j & 7;
            const int l    = (j >> 3) & 63;
            const int tile = j >> 9;     // 0..19
            const int nt   = tile % 5;
            const int kt   = tile / 5;
            const int o    = nt * 16 + (l & 15);
            const int k    = kt * 32 + ((l >> 4) << 3) + e;
            const float q  = clip127(rintf(Wp[o * 128 + k] / s));
            bf[j] = f2bf(q);
        }
        if (tid == 0) ws[1] = s;
    } else {
        for (int i = tid; i < n; i += 256) {
            const float q = clip127(rintf(src[i] / s));
            if (t == 1) {            // Wf1 [64][2]
                ws[OFF_WF1 + i] = s * q;
            } else if (t == 2) {     // Wf2 [32][64] -> transposed [64][32]
                int o = i / 64, c = i % 64;
                ws[OFF_WF2 + c * 32 + o] = s * q;
            } else {                 // Wd [128][9]: keep integer q
                ws[OFF_WD + i] = q;
            }
        }
        if (tid == 0 && t == 3) ws[0] = s;
    }
}

// ---------------- kernel 1a: convc1 (196 -> 96) ----------------
// 256 px/block, 8 waves. 32-ch slab double-buffer staged via global_load_lds
// where EACH instruction reads 1 KB CONTIGUOUS (one channel-row chunk) —
// 8x the read granule of prior rounds. LDS 66 KB -> 2 blocks/CU = 16 waves/CU
// (4/SIMD), 2x prior occupancy. Counted-vmcnt scheme proven exact by FIFO
// analysis (b-frag waits drain older stages; explicit vmcnt(4) guards iter 0).
#define SLAB 33024   // 32 ch * 258 dwords * 4 B
#define CSTR 1032    // channel stride in slab (258 dwords): 8-ch group -> +16 banks
#define TS8  260     // t8 transpose-row stride (bytes): 256 px + 4 pad
__global__ __launch_bounds__(512, 4) void k1_convc1(
    const float* __restrict__ corr, const float* __restrict__ bc1,
    const float* __restrict__ ws,   signed char* __restrict__ cfq)
{
    __shared__ __align__(1024) char smem[2 * SLAB];   // slabs; t8 aliases slab A

    const int tid  = threadIdx.x;
    const int w    = tid >> 6;       // 0..7
    const int l    = tid & 63;
    const int bid  = blockIdx.x;
    const int wgid = (bid & 7) * 75 + (bid >> 3);   // XCD swizzle (600 = 8*75)
    const int p0   = wgid * 256;                    // 19200 % 256 == 0
    const int b    = p0 / HW;
    const int hw0  = p0 % HW;
    const float* cp = corr + (size_t)b * CORC * HW + hw0;

    const short8* Bfr = (const short8*)((const unsigned short*)ws + 32);

    // STAGE: 32 instrs (4/wave), each loads ONE channel's 1 KB (256 px) chunk.
    // lane l writes dst base + l*16: linear, matches [ch][px] slab layout.
#define STAGE(KT, BASE)                                                               \
    {   _Pragma("unroll")                                                             \
        for (int i = 0; i < 4; ++i) {                                                 \
            const int cl = i * 8 + w;                                                 \
            int ch = (KT) * 32 + cl;                                                  \
            ch = ch < CORC ? ch : (CORC - 1);                                         \
            const char* src = (const char*)cp + (size_t)ch * (HW * 4) + l * 16;       \
            u32* dst = (u32*)(smem + (BASE) + cl * CSTR);                             \
            __builtin_amdgcn_global_load_lds(                                         \
                (const __attribute__((address_space(1))) u32*)src,                    \
                (__attribute__((address_space(3))) u32*)dst, 16, 0, 0);               \
        }                                                                             }

    f32x4 a00 = {0.f,0.f,0.f,0.f}, a01 = a00, a02 = a00, a03 = a00, a04 = a00, a05 = a00;
    f32x4 a10 = a00, a11 = a00, a12 = a00, a13 = a00, a14 = a00, a15 = a00;

    STAGE(0, 0)
    STAGE(1, SLAB)

    const int pixoff = (w * 32 + (l & 15)) * 4;   // m-tile-0 pixel byte offset
    const int chbase = (l >> 4) << 3;             // fragment k sub-channel base

#pragma unroll
    for (int kt = 0; kt < 7; ++kt) {
        const int base = (kt & 1) ? SLAB : 0;

        // own stage(kt) guard: active only at kt=0 (steady-state: prior iter's
        // b-frag waits already drained stage(kt) via FIFO order).
        asm volatile("s_waitcnt vmcnt(4)" ::: "memory");
        __builtin_amdgcn_sched_barrier(0);
        __builtin_amdgcn_s_barrier();                      // all waves: slab(kt) ready
        __builtin_amdgcn_sched_barrier(0);

        // ---- ds_read slab(kt) fragments into registers ----
        float v0[8], v1[8];
#pragma unroll
        for (int e = 0; e < 8; ++e) {
            const char* ap = smem + base + (chbase + e) * CSTR + pixoff;
            v0[e] = *(const float*)ap;          // m-tile 0
            v1[e] = *(const float*)(ap + 64);   // m-tile 1 (+16 px)
        }
        __builtin_amdgcn_sched_barrier(0);
        asm volatile("s_waitcnt lgkmcnt(0)" ::: "memory");
        __builtin_amdgcn_sched_barrier(0);
        __builtin_amdgcn_s_barrier();                       // all waves done reading
        __builtin_amdgcn_sched_barrier(0);

        // ---- B-frags first (their minimal waits drain the older stage) ----
        const short8 b0 = Bfr[(kt * 6 + 0) * 64 + l];
        const short8 b1 = Bfr[(kt * 6 + 1) * 64 + l];
        const short8 b2 = Bfr[(kt * 6 + 2) * 64 + l];
        const short8 b3 = Bfr[(kt * 6 + 3) * 64 + l];
        const short8 b4 = Bfr[(kt * 6 + 4) * 64 + l];
        const short8 b5 = Bfr[(kt * 6 + 5) * 64 + l];
        __builtin_amdgcn_sched_barrier(0);

        if (kt < 5) STAGE(kt + 2, base)            // refill just-freed slab
        __builtin_amdgcn_sched_barrier(0);

        // ---- RNE hi/lo bf16 split (bit-identical to rounds 7/9/10/11) ----
        short8 h0_, l0_, h1_, l1_;
#pragma unroll
        for (int e = 0; e < 8; ++e) {
            const float va = v0[e], vb = v1[e];
            const unsigned short ha = f2bf(va);
            const unsigned short hb = f2bf(vb);
            h0_[e] = (short)ha; h1_[e] = (short)hb;
            l0_[e] = (short)f2bf(va - __uint_as_float((unsigned int)ha << 16));
            l1_[e] = (short)f2bf(vb - __uint_as_float((unsigned int)hb << 16));
        }

#define MF(BB_, A0, A1)                                                          \
        A0 = __builtin_amdgcn_mfma_f32_16x16x32_bf16(l0_, BB_, A0, 0, 0, 0);     \
        A0 = __builtin_amdgcn_mfma_f32_16x16x32_bf16(h0_, BB_, A0, 0, 0, 0);     \
        A1 = __builtin_amdgcn_mfma_f32_16x16x32_bf16(l1_, BB_, A1, 0, 0, 0);     \
        A1 = __builtin_amdgcn_mfma_f32_16x16x32_bf16(h1_, BB_, A1, 0, 0, 0);
        MF(b0, a00, a10) MF(b1, a01, a11) MF(b2, a02, a12)
        MF(b3, a03, a13) MF(b4, a04, a14) MF(b5, a05, a15)
#undef MF
    }
#undef STAGE

    // ---- epilogue: quant chain -> t8 transpose buffer (aliases slab A).
    // Safe: final iter's 2nd barrier guarantees all slab reads completed. ----
    const float sc1 = ws[2];
    signed char* t8 = (signed char*)smem;   // [96 out][256 px], stride 260

#define EPI(ACC, NT, TILE)                                                        \
    {   const int out = (NT) * 16 + (l & 15);                                     \
        const float bias = bc1[out];                                              \
        _Pragma("unroll")                                                         \
        for (int i = 0; i < 4; ++i) {                                             \
            const int prow = w * 32 + (TILE) * 16 + ((l >> 4) << 2) + i;          \
            float v  = fmaf(sc1, ACC[i], bias);                                   \
            float aq = AS_ * clip127(rintf(v / AS_));                             \
            float r  = fmaxf(aq, 0.f);                                            \
            float kk = fminf(rintf(r * 32.f), 127.f);                             \
            float cf = kk * FS_;                                                  \
            float q8 = clip127(rintf(cf / AS_));                                  \
            t8[out * TS8 + prow] = (signed char)(int)q8;                          \
        }                                                                         }
    EPI(a00, 0, 0) EPI(a01, 1, 0) EPI(a02, 2, 0) EPI(a03, 3, 0) EPI(a04, 4, 0) EPI(a05, 5, 0)
    EPI(a10, 0, 1) EPI(a11, 1, 1) EPI(a12, 2, 1) EPI(a13, 3, 1) EPI(a14, 4, 1) EPI(a15, 5, 1)
#undef EPI
    __syncthreads();

    // ---- coalesced store: 96 rows x 256 bytes ----
#pragma unroll
    for (int r = 0; r < 12; ++r) {
        const int d   = r * 512 + tid;     // 6144 dwords total
        const int out = d >> 6;
        const int pd  = d & 63;
        const u32 v = *(const u32*)(t8 + out * TS8 + pd * 4);
        *(u32*)(cfq + (size_t)(b * 128 + out) * HW + hw0 + pd * 4) = v;
    }
}

// ---------------- kernel 1b: flo path (convf1 2->64, convf2 64->32) ----------------
typedef __attribute__((ext_vector_type(16))) float f32x16;
__global__ __launch_bounds__(256) void k1_flo(
    const float* __restrict__ flow, const float* __restrict__ bf1,
    const float* __restrict__ bf2,  const float* __restrict__ ws,
    signed char* __restrict__ cfq)
{
    const int p  = blockIdx.x * 256 + threadIdx.x;
    const int b  = p / HW;
    const int hw = p % HW;

    const float f0 = flow[(size_t)(b * 2) * HW + hw];
    const float f1 = flow[(size_t)(b * 2 + 1) * HW + hw];

    f32x16 a2a, a2b;
#pragma unroll
    for (int j = 0; j < 16; ++j) { a2a[j] = 0.f; a2b[j] = 0.f; }

    for (int c = 0; c < 64; ++c) {
        const float w0 = ws[OFF_WF1 + 2 * c];
        const float w1 = ws[OFF_WF1 + 2 * c + 1];
        float v  = fmaf(f0, w0, fmaf(f1, w1, bf1[c]));
        float r  = fmaxf(v, 0.f);
        float af = AS_ * fminf(rintf(r / AS_), 127.f);
        const float* w2 = ws + OFF_WF2 + c * 32;
#pragma unroll
        for (int j = 0; j < 16; ++j) {
            a2a[j] = fmaf(af, w2[j],      a2a[j]);
            a2b[j] = fmaf(af, w2[16 + j], a2b[j]);
        }
    }

    signed char* op = cfq + (size_t)b * 128 * HW + (size_t)96 * HW + hw;
#define FLOEPI(ACC, BASE)                                                        \
    _Pragma("unroll")                                                            \
    for (int j = 0; j < 16; ++j) {                                               \
        const int o = (BASE) + j;                                                \
        float v  = ACC[j] + bf2[o];                                              \
        float aq = AS_ * clip127(rintf(v / AS_));                                \
        float r  = fmaxf(aq, 0.f);                                               \
        float kk = fminf(rintf(r * 32.f), 127.f);                                \
        float cf = kk * FS_;                                                     \
        float q8 = clip127(rintf(cf / AS_));                                     \
        op[(size_t)o * HW] = (signed char)(int)q8;                               \
    }
    FLOEPI(a2a, 0) FLOEPI(a2b, 16)
#undef FLOEPI
}

// ---------------- kernel 2: depthwise 3x3 (VALU, exact) + pointwise via MFMA ----------------
#define STG_STRIDE 44
__global__ __launch_bounds__(256) void k2_dwpw(
    const float* __restrict__ flow, const float* __restrict__ bd,
    const float* __restrict__ bp,   const float* __restrict__ ws,
    const signed char* __restrict__ cfq, float* __restrict__ out)
{
    __shared__ signed char stage[4 * 128 * STG_STRIDE];   // [row][c][44]
    __shared__ unsigned short afrag[64 * 136];            // [pix][136] bf16 codes

    const int tid = threadIdx.x;
    const int bid = blockIdx.x;
    const int b   = bid / 300;          // 60 row-tiles * 5 col-tiles
    const int rem = bid % 300;
    const int h0  = (rem / 5) * 2;
    const int w0  = (rem % 5) * 32;

    for (int j = tid; j < 5120; j += 256) {
        const int i   = j % 10;
        const int c   = (j / 10) % 128;
        const int row = j / 1280;
        const int h   = h0 - 1 + row;
        const int wb  = w0 - 4 + 4 * i;
        unsigned int v = 0u;
        if (h >= 0 && h < HH && wb >= 0 && wb <= WW - 4)
            v = *(const unsigned int*)(cfq + ((size_t)(b * 128 + c) * HW + (size_t)h * WW + wb));
        *(unsigned int*)(stage + (row * 128 + c) * STG_STRIDE + i * 4) = v;
    }
    __syncthreads();

    const int c0 = tid & 63;
    const int pg = tid >> 6;
    const float sd = ws[0], sp = ws[1];
    const float ASsd = AS_ * sd;

    float wd0[9], wd1[9];
#pragma unroll
    for (int t9 = 0; t9 < 9; ++t9) {
        wd0[t9] = ws[OFF_WD + c0 * 9 + t9];
        wd1[t9] = ws[OFF_WD + (c0 + 64) * 9 + t9];
    }
    const float bd0 = bd[c0], bd1 = bd[c0 + 64];

#pragma unroll
    for (int pp = 0; pp < 16; ++pp) {
        const int pix = pg * 16 + pp;
        const int r   = pix >> 5;
        const int col = pix & 31;
        float s0 = 0.f, s1 = 0.f;
#pragma unroll
        for (int dy = 0; dy < 3; ++dy) {
            const int rb = (r + dy) * 128;
            const int xb = 3 + col;
#pragma unroll
            for (int dd = 0; dd < 3; ++dd) {
                s0 = fmaf((float)stage[(rb + c0     ) * STG_STRIDE + xb + dd], wd0[dy * 3 + dd], s0);
                s1 = fmaf((float)stage[(rb + c0 + 64) * STG_STRIDE + xb + dd], wd1[dy * 3 + dd], s1);
            }
        }
        const float q0 = clip127(rintf(fmaf(ASsd, s0, bd0) / AS_));
        const float q1 = clip127(rintf(fmaf(ASsd, s1, bd1) / AS_));
        afrag[pix * 136 + c0]      = f2bf(q0);
        afrag[pix * 136 + c0 + 64] = f2bf(q1);
    }
    __syncthreads();

    const int wv = tid >> 6;
    const int l  = tid & 63;
    const unsigned short* A = afrag + (size_t)(wv * 16 + (l & 15)) * 136 + ((l >> 4) << 3);
    const short8* Bfr = (const short8*)((const unsigned short*)ws + OFF_WPQ_US);

    f32x4 pc0 = {0.f,0.f,0.f,0.f}, pc1 = pc0, pc2 = pc0, pc3 = pc0, pc4 = pc0;

#define PTSTEP(ACC, KT, NT)                                                      \
    {   short8 bq = Bfr[((KT) * 5 + (NT)) * 64 + l];                             \
        ACC = __builtin_amdgcn_mfma_f32_16x16x32_bf16(a_, bq, ACC, 0, 0, 0);     }
#pragma unroll
    for (int kt = 0; kt < 4; ++kt) {
        short8 a_ = *(const short8*)(A + kt * 32);
        PTSTEP(pc0, kt, 0) PTSTEP(pc1, kt, 1) PTSTEP(pc2, kt, 2)
        PTSTEP(pc3, kt, 3) PTSTEP(pc4, kt, 4)
    }
#undef PTSTEP

    const float ASsp = AS_ * sp;
    float* ob = out + (size_t)b * 82 * HW;

#define PEPI(ACC, NT)                                                            \
    {   const int o = (NT) * 16 + (l & 15);                                      \
        const float bias = bp[o];                                                \
        _Pragma("unroll")                                                        \
        for (int i = 0; i < 4; ++i) {                                            \
            const int pix = wv * 16 + ((l >> 4) << 2) + i;                       \
            const int hw  = (h0 + (pix >> 5)) * WW + w0 + (pix & 31);            \
            float v = fmaf(ASsp, ACC[i], bias);                                  \
            float r = fmaxf(v, 0.f);                                             \
            float k = fminf(rintf(r * 32.f), 127.f);                             \
            ob[(size_t)o * HW + hw] = k * FS_;                                   \
        }                                                                        }
    PEPI(pc0, 0) PEPI(pc1, 1) PEPI(pc2, 2) PEPI(pc3, 3) PEPI(pc4, 4)
#undef PEPI

    if (tid < 128) {
        const int ch  = tid >> 6;
        const int pix = tid & 63;
        const int hw  = (h0 + (pix >> 5)) * WW + w0 + (pix & 31);
        const float f = flow[(size_t)(b * 2 + ch) * HW + hw];
        const float k = clip127(rintf(f * 32.f));
        ob[(size_t)(80 + ch) * HW + hw] = k * FS_;
    }
}

// ---------------- launcher ----------------
extern "C" void kernel_launch(void* const* d_in, const int* in_sizes, int n_in,
                              void* d_out, int out_size, void* d_ws, size_t ws_size,
                              hipStream_t stream) {
    const float* flow = (const float*)d_in[0];
    const float* corr = (const float*)d_in[1];
    const float* Wc1  = (const float*)d_in[2];
    const float* bc1  = (const float*)d_in[3];
    const float* Wf1  = (const float*)d_in[4];
    const float* bf1  = (const float*)d_in[5];
    const float* Wf2  = (const float*)d_in[6];
    const float* bf2  = (const float*)d_in[7];
    const float* Wd   = (const float*)d_in[8];
    const float* bd   = (const float*)d_in[9];
    const float* Wp   = (const float*)d_in[10];
    const float* bp   = (const float*)d_in[11];

    float* ws = (float*)d_ws;
    signed char* cfq = (signed char*)d_ws + CFQ_BYTE_OFF;
    float* out = (float*)d_out;

    quant_weights<<<5, 256, 0, stream>>>(Wc1, Wf1, Wf2, Wd, Wp, ws);
    k1_convc1<<<NPIX / 256, 512, 0, stream>>>(corr, bc1, ws, cfq);
    k1_flo<<<NPIX / 256, 256, 0, stream>>>(flow, bf1, bf2, ws, cfq);
    k2_dwpw<<<2400, 256, 0, stream>>>(flow, bd, bp, ws, cfq, out);
}

// Round 13
// 163.228 us; speedup vs baseline: 1.0372x; 1.0372x over previous
//
#include <hip/hip_runtime.h>
#include <hip/hip_bf16.h>
#include <cstddef>

// ---------------- problem constants ----------------
#define BB   8
#define HH   120
#define WW   160
#define HW   19200          // HH*WW
#define NPIX 153600         // BB*HW
#define CORC 196

#define AS_  ((float)(6.0/127.0))   // ACT_SCALE
#define FS_  0.03125f               // FLOW_SCALE = 3.96875/127 = 2^-5 exactly

// ws layout:
//   float[0]=sd, float[1]=sp, float[2]=s_c1
//   ushort[32 .. 32+21504)      : convc1 B-frags (bf16 int codes)
//   float[OFF_WF1 .. +128)      : Wf1 dequant
//   float[OFF_WF2 .. +2048)     : Wf2 dequant transposed
//   float[OFF_WD  .. +1152)     : Wd integer codes
//   ushort[OFF_WPQ_US .. +10240): Wp B-frags (bf16 int codes)
#define OFF_WF1 18832
#define OFF_WF2 18960
#define OFF_WD  21008
#define OFF_WPQ_US 44320
#define CFQ_BYTE_OFF 131072         // int8 activation buffer, 8*128*19200 bytes

typedef __attribute__((ext_vector_type(8)))  short short8;
typedef __attribute__((ext_vector_type(4)))  float f32x4;
typedef unsigned int u32;

__device__ __forceinline__ float clip127(float x) {
    return fminf(fmaxf(x, -127.f), 127.f);
}

// round-to-nearest-even fp32 -> bf16 (finite inputs only)
__device__ __forceinline__ unsigned short f2bf(float x) {
    unsigned int u = __float_as_uint(x);
    unsigned int r = (u + 0x7fffu + ((u >> 16) & 1u)) >> 16;
    return (unsigned short)r;
}

// ---------------- kernel 0: weight fake-quant ----------------
__global__ __launch_bounds__(256) void quant_weights(
    const float* __restrict__ Wc1, const float* __restrict__ Wf1,
    const float* __restrict__ Wf2, const float* __restrict__ Wd,
    const float* __restrict__ Wp,  float* __restrict__ ws)
{
    __shared__ float red[256];
    const int t = blockIdx.x;
    const float* src = (t == 0) ? Wc1 : (t == 1) ? Wf1 : (t == 2) ? Wf2 : (t == 3) ? Wd : Wp;
    const int n = (t == 0) ? 18816 : (t == 1) ? 128 : (t == 2) ? 2048 : (t == 3) ? 1152 : 10240;
    const int tid = threadIdx.x;

    float m = 0.f;
    for (int i = tid; i < n; i += 256) m = fmaxf(m, fabsf(src[i]));
    red[tid] = m;
    __syncthreads();
    for (int s = 128; s > 0; s >>= 1) {
        if (tid < s) red[tid] = fmaxf(red[tid], red[tid + s]);
        __syncthreads();
    }
    const float s = red[0] / 127.0f + 1e-12f;

    if (t == 0) {
        // convc1 weights as MFMA B-frags: o = nt*16+(l&15), k = kt*32+((l>>4)<<3)+e
        unsigned short* bf = (unsigned short*)ws + 32;
        for (int j = tid; j < 21504; j += 256) {
            const int e    = j & 7;
            const int l    = (j >> 3) & 63;
            const int tile = j >> 9;
            const int nt   = tile % 6;
            const int kt   = tile / 6;
            const int out  = nt * 16 + (l & 15);
            const int k    = kt * 32 + ((l >> 4) << 3) + e;
            float q = 0.f;
            if (k < 196) q = clip127(rintf(Wc1[out * 196 + k] / s));
            bf[j] = f2bf(q);
        }
        if (tid == 0) ws[2] = s;
    } else if (t == 4) {
        // pointwise weights as MFMA B-frags: 5 n-tiles x 4 k-steps
        unsigned short* bf = (unsigned short*)ws + OFF_WPQ_US;
        for (int j = tid; j < 10240; j += 256) {
            const int e    = j & 7;
            const int l    = (j >> 3) & 63;
            const int tile = j >> 9;     // 0..19
            const int nt   = tile % 5;
            const int kt   = tile / 5;
            const int o    = nt * 16 + (l & 15);
            const int k    = kt * 32 + ((l >> 4) << 3) + e;
            const float q  = clip127(rintf(Wp[o * 128 + k] / s));
            bf[j] = f2bf(q);
        }
        if (tid == 0) ws[1] = s;
    } else {
        for (int i = tid; i < n; i += 256) {
            const float q = clip127(rintf(src[i] / s));
            if (t == 1) {            // Wf1 [64][2]
                ws[OFF_WF1 + i] = s * q;
            } else if (t == 2) {     // Wf2 [32][64] -> transposed [64][32]
                int o = i / 64, c = i % 64;
                ws[OFF_WF2 + c * 32 + o] = s * q;
            } else {                 // Wd [128][9]: keep integer q
                ws[OFF_WD + i] = q;
            }
        }
        if (tid == 0 && t == 3) ws[0] = s;
    }
}

// ---------------- kernel 1a: convc1 (196 -> 96) ----------------
// Depth-5 pipeline, B-frags preloaded to VGPRs (vmcnt FIFO = stages ONLY).
// 64 px/block, 4 waves: waves (0,1)->px 0-31, (2,3)->px 32-63; wave w covers
// n-tiles (w&1)*3..+2 (3 of 6) so 21 short8 B-regs fit. Per kt: wait own
// stage (exact per-kt vmcnt constant), barrier, ds_read, lgkmcnt+barrier,
// restage slab kt%5 for kt+5 (5-iter slack ~2000cyc > ~1700cyc latency).
#define NSLAB 5
#define SLAB_B 8192          // 32 ch x 64 px x 4 B
#define CSTR 256             // channel stride (bytes) inside slab
#define TS8  68              // t8 transpose-row stride (bytes)
__global__ __launch_bounds__(256, 3) void k1_convc1(
    const float* __restrict__ corr, const float* __restrict__ bc1,
    const float* __restrict__ ws,   signed char* __restrict__ cfq)
{
    __shared__ __align__(1024) char smem[NSLAB * SLAB_B];   // 40 KB; t8 aliases

    const int tid  = threadIdx.x;
    const int w    = tid >> 6;       // 0..3
    const int l    = tid & 63;
    const int bid  = blockIdx.x;
    const int wgid = (bid & 7) * 300 + (bid >> 3);   // XCD swizzle (2400 = 8*300)
    const int p0   = wgid * 64;                      // 19200 % 64 == 0
    const int b    = p0 / HW;
    const int hw0  = p0 % HW;
    const float* cp = corr + (size_t)b * CORC * HW + hw0;

    const short8* Bfr = (const short8*)((const unsigned short*)ws + 32);
    const int nbase = (w & 1) * 3;                   // this wave's n-tile base

    // ---- B preload FIRST: occupies the head of the vmcnt FIFO ----
#define DECLB(KT)                                                              \
    const short8 b##KT##_0 = Bfr[((KT) * 6 + nbase + 0) * 64 + l];             \
    const short8 b##KT##_1 = Bfr[((KT) * 6 + nbase + 1) * 64 + l];             \
    const short8 b##KT##_2 = Bfr[((KT) * 6 + nbase + 2) * 64 + l];
    DECLB(0) DECLB(1) DECLB(2) DECLB(3) DECLB(4) DECLB(5) DECLB(6)
#undef DECLB
    __builtin_amdgcn_sched_barrier(0);

    // STAGE: 2 instrs/wave, each loads 1 KB contiguous = 4 channels x 64 px.
    // dst wave-uniform; HW writes lane l at dst + l*16 -> [ch][px] linear.
#define STAGE(KT)                                                                     \
    {   char* dbase = smem + ((KT) % NSLAB) * SLAB_B;                                 \
        _Pragma("unroll")                                                             \
        for (int i = 0; i < 2; ++i) {                                                 \
            const int cg = w * 2 + i;            /* 4-ch group 0..7 */                \
            int chl = (KT) * 32 + cg * 4 + (l >> 4);                                  \
            chl = chl < CORC ? chl : (CORC - 1);                                      \
            const char* src = (const char*)cp + (size_t)chl * (HW * 4)                \
                              + (l & 15) * 16;                                        \
            u32* dst = (u32*)(dbase + cg * 1024);                                     \
            __builtin_amdgcn_global_load_lds(                                         \
                (const __attribute__((address_space(1))) u32*)src,                    \
                (__attribute__((address_space(3))) u32*)dst, 16, 0, 0);               \
        }                                                                             }

    STAGE(0) STAGE(1) STAGE(2) STAGE(3) STAGE(4)

    const int pixoff = ((w >> 1) * 32 + (l & 15)) * 4;   // m-tile-0 pixel byte off
    const int chbase = (l >> 4) << 3;                    // fragment k sub-channel

    f32x4 ac00 = {0.f,0.f,0.f,0.f}, ac01 = ac00, ac02 = ac00;  // m-tile 0
    f32x4 ac10 = ac00, ac11 = ac00, ac12 = ac00;               // m-tile 1

#define MF(BB_, A0, A1)                                                          \
        A0 = __builtin_amdgcn_mfma_f32_16x16x32_bf16(l0_, BB_, A0, 0, 0, 0);     \
        A0 = __builtin_amdgcn_mfma_f32_16x16x32_bf16(h0_, BB_, A0, 0, 0, 0);     \
        A1 = __builtin_amdgcn_mfma_f32_16x16x32_bf16(l1_, BB_, A1, 0, 0, 0);     \
        A1 = __builtin_amdgcn_mfma_f32_16x16x32_bf16(h1_, BB_, A1, 0, 0, 0);

    // Per-kt vmcnt constants (2 loads/stage/wave):
    // kt0: B(21)+S0..S4(10)=31 outstanding; <=8 drains B+S0 exactly.
    // kt1,2: 10 outstanding -> 8.  kt3: 8->6.  kt4: 6->4.  kt5: 4->2.  kt6: 2->0.
#define KSTEP(KT, WN)                                                             \
    {   asm volatile("s_waitcnt vmcnt(" #WN ")" ::: "memory");                    \
        __builtin_amdgcn_sched_barrier(0);                                        \
        __builtin_amdgcn_s_barrier();                /* slab(KT) ready */         \
        __builtin_amdgcn_sched_barrier(0);                                        \
        const char* abase = smem + ((KT) % NSLAB) * SLAB_B;                       \
        float v0[8], v1[8];                                                       \
        _Pragma("unroll")                                                         \
        for (int e = 0; e < 8; ++e) {                                             \
            const char* ap = abase + (chbase + e) * CSTR + pixoff;                \
            v0[e] = *(const float*)ap;                                            \
            v1[e] = *(const float*)(ap + 64);                                     \
        }                                                                         \
        __builtin_amdgcn_sched_barrier(0);                                        \
        asm volatile("s_waitcnt lgkmcnt(0)" ::: "memory");                        \
        __builtin_amdgcn_sched_barrier(0);                                        \
        __builtin_amdgcn_s_barrier();                /* slab(KT) free */          \
        __builtin_amdgcn_sched_barrier(0);                                        \
        if ((KT) + NSLAB < 7) STAGE((KT) + NSLAB)                                 \
        __builtin_amdgcn_sched_barrier(0);                                        \
        short8 h0_, l0_, h1_, l1_;                                                \
        _Pragma("unroll")                                                         \
        for (int e = 0; e < 8; ++e) {                                             \
            const float va = v0[e], vb = v1[e];                                   \
            const unsigned short ha = f2bf(va);                                   \
            const unsigned short hb = f2bf(vb);                                   \
            h0_[e] = (short)ha; h1_[e] = (short)hb;                               \
            l0_[e] = (short)f2bf(va - __uint_as_float((unsigned int)ha << 16));   \
            l1_[e] = (short)f2bf(vb - __uint_as_float((unsigned int)hb << 16));   \
        }                                                                         \
        MF(b##KT##_0, ac00, ac10) MF(b##KT##_1, ac01, ac11)                       \
        MF(b##KT##_2, ac02, ac12)                                                 }

    KSTEP(0, 8) KSTEP(1, 8) KSTEP(2, 8) KSTEP(3, 6)
    KSTEP(4, 4) KSTEP(5, 2) KSTEP(6, 0)
#undef KSTEP
#undef MF
#undef STAGE

    // ---- epilogue: quant chain -> t8 transpose buffer (aliases slabs).
    // Safe: kt6's second barrier ensured all slab reads completed. ----
    const float sc1 = ws[2];
    signed char* t8 = (signed char*)smem;   // [96 out][64 px], stride 68

#define EPI(ACC, NT, TILE)                                                        \
    {   const int out = (nbase + (NT)) * 16 + (l & 15);                           \
        const float bias = bc1[out];                                              \
        _Pragma("unroll")                                                         \
        for (int i = 0; i < 4; ++i) {                                             \
            const int prow = (w >> 1) * 32 + (TILE) * 16 + ((l >> 4) << 2) + i;   \
            float v  = fmaf(sc1, ACC[i], bias);                                   \
            float aq = AS_ * clip127(rintf(v / AS_));                             \
            float r  = fmaxf(aq, 0.f);                                            \
            float kk = fminf(rintf(r * 32.f), 127.f);                             \
            float cf = kk * FS_;                                                  \
            float q8 = clip127(rintf(cf / AS_));                                  \
            t8[out * TS8 + prow] = (signed char)(int)q8;                          \
        }                                                                         }
    EPI(ac00, 0, 0) EPI(ac01, 1, 0) EPI(ac02, 2, 0)
    EPI(ac10, 0, 1) EPI(ac11, 1, 1) EPI(ac12, 2, 1)
#undef EPI
    __syncthreads();

    // ---- coalesced store: 96 rows x 64 bytes ----
#pragma unroll
    for (int r = 0; r < 6; ++r) {
        const int d   = r * 256 + tid;     // 1536 dwords total
        const int out = d >> 4;
        const int pd  = d & 15;
        const u32 v = *(const u32*)(t8 + out * TS8 + pd * 4);
        *(u32*)(cfq + (size_t)(b * 128 + out) * HW + hw0 + pd * 4) = v;
    }
}

// ---------------- kernel 1b: flo path (convf1 2->64, convf2 64->32) ----------------
typedef __attribute__((ext_vector_type(16))) float f32x16;
__global__ __launch_bounds__(256) void k1_flo(
    const float* __restrict__ flow, const float* __restrict__ bf1,
    const float* __restrict__ bf2,  const float* __restrict__ ws,
    signed char* __restrict__ cfq)
{
    const int p  = blockIdx.x * 256 + threadIdx.x;
    const int b  = p / HW;
    const int hw = p % HW;

    const float f0 = flow[(size_t)(b * 2) * HW + hw];
    const float f1 = flow[(size_t)(b * 2 + 1) * HW + hw];

    f32x16 a2a, a2b;
#pragma unroll
    for (int j = 0; j < 16; ++j) { a2a[j] = 0.f; a2b[j] = 0.f; }

    for (int c = 0; c < 64; ++c) {
        const float w0 = ws[OFF_WF1 + 2 * c];
        const float w1 = ws[OFF_WF1 + 2 * c + 1];
        float v  = fmaf(f0, w0, fmaf(f1, w1, bf1[c]));
        float r  = fmaxf(v, 0.f);
        float af = AS_ * fminf(rintf(r / AS_), 127.f);
        const float* w2 = ws + OFF_WF2 + c * 32;
#pragma unroll
        for (int j = 0; j < 16; ++j) {
            a2a[j] = fmaf(af, w2[j],      a2a[j]);
            a2b[j] = fmaf(af, w2[16 + j], a2b[j]);
        }
    }

    signed char* op = cfq + (size_t)b * 128 * HW + (size_t)96 * HW + hw;
#define FLOEPI(ACC, BASE)                                                        \
    _Pragma("unroll")                                                            \
    for (int j = 0; j < 16; ++j) {                                               \
        const int o = (BASE) + j;                                                \
        float v  = ACC[j] + bf2[o];                                              \
        float aq = AS_ * clip127(rintf(v / AS_));                                \
        float r  = fmaxf(aq, 0.f);                                               \
        float kk = fminf(rintf(r * 32.f), 127.f);                                \
        float cf = kk * FS_;                                                     \
        float q8 = clip127(rintf(cf / AS_));                                     \
        op[(size_t)o * HW] = (signed char)(int)q8;                               \
    }
    FLOEPI(a2a, 0) FLOEPI(a2b, 16)
#undef FLOEPI
}

// ---------------- kernel 2: depthwise 3x3 (VALU, exact) + pointwise via MFMA ----------------
#define STG_STRIDE 44
__global__ __launch_bounds__(256) void k2_dwpw(
    const float* __restrict__ flow, const float* __restrict__ bd,
    const float* __restrict__ bp,   const float* __restrict__ ws,
    const signed char* __restrict__ cfq, float* __restrict__ out)
{
    __shared__ signed char stage[4 * 128 * STG_STRIDE];   // [row][c][44]
    __shared__ unsigned short afrag[64 * 136];            // [pix][136] bf16 codes

    const int tid = threadIdx.x;
    const int bid = blockIdx.x;
    const int b   = bid / 300;          // 60 row-tiles * 5 col-tiles
    const int rem = bid % 300;
    const int h0  = (rem / 5) * 2;
    const int w0  = (rem % 5) * 32;

    for (int j = tid; j < 5120; j += 256) {
        const int i   = j % 10;
        const int c   = (j / 10) % 128;
        const int row = j / 1280;
        const int h   = h0 - 1 + row;
        const int wb  = w0 - 4 + 4 * i;
        unsigned int v = 0u;
        if (h >= 0 && h < HH && wb >= 0 && wb <= WW - 4)
            v = *(const unsigned int*)(cfq + ((size_t)(b * 128 + c) * HW + (size_t)h * WW + wb));
        *(unsigned int*)(stage + (row * 128 + c) * STG_STRIDE + i * 4) = v;
    }
    __syncthreads();

    const int c0 = tid & 63;
    const int pg = tid >> 6;
    const float sd = ws[0], sp = ws[1];
    const float ASsd = AS_ * sd;

    float wd0[9], wd1[9];
#pragma unroll
    for (int t9 = 0; t9 < 9; ++t9) {
        wd0[t9] = ws[OFF_WD + c0 * 9 + t9];
        wd1[t9] = ws[OFF_WD + (c0 + 64) * 9 + t9];
    }
    const float bd0 = bd[c0], bd1 = bd[c0 + 64];

#pragma unroll
    for (int pp = 0; pp < 16; ++pp) {
        const int pix = pg * 16 + pp;
        const int r   = pix >> 5;
        const int col = pix & 31;
        float s0 = 0.f, s1 = 0.f;
#pragma unroll
        for (int dy = 0; dy < 3; ++dy) {
            const int rb = (r + dy) * 128;
            const int xb = 3 + col;
#pragma unroll
            for (int dd = 0; dd < 3; ++dd) {
                s0 = fmaf((float)stage[(rb + c0     ) * STG_STRIDE + xb + dd], wd0[dy * 3 + dd], s0);
                s1 = fmaf((float)stage[(rb + c0 + 64) * STG_STRIDE + xb + dd], wd1[dy * 3 + dd], s1);
            }
        }
        const float q0 = clip127(rintf(fmaf(ASsd, s0, bd0) / AS_));
        const float q1 = clip127(rintf(fmaf(ASsd, s1, bd1) / AS_));
        afrag[pix * 136 + c0]      = f2bf(q0);
        afrag[pix * 136 + c0 + 64] = f2bf(q1);
    }
    __syncthreads();

    const int wv = tid >> 6;
    const int l  = tid & 63;
    const unsigned short* A = afrag + (size_t)(wv * 16 + (l & 15)) * 136 + ((l >> 4) << 3);
    const short8* Bfr = (const short8*)((const unsigned short*)ws + OFF_WPQ_US);

    f32x4 pc0 = {0.f,0.f,0.f,0.f}, pc1 = pc0, pc2 = pc0, pc3 = pc0, pc4 = pc0;

#define PTSTEP(ACC, KT, NT)                                                      \
    {   short8 bq = Bfr[((KT) * 5 + (NT)) * 64 + l];                             \
        ACC = __builtin_amdgcn_mfma_f32_16x16x32_bf16(a_, bq, ACC, 0, 0, 0);     }
#pragma unroll
    for (int kt = 0; kt < 4; ++kt) {
        short8 a_ = *(const short8*)(A + kt * 32);
        PTSTEP(pc0, kt, 0) PTSTEP(pc1, kt, 1) PTSTEP(pc2, kt, 2)
        PTSTEP(pc3, kt, 3) PTSTEP(pc4, kt, 4)
    }
#undef PTSTEP

    const float ASsp = AS_ * sp;
    float* ob = out + (size_t)b * 82 * HW;

#define PEPI(ACC, NT)                                                            \
    {   const int o = (NT) * 16 + (l & 15);                                      \
        const float bias = bp[o];                                                \
        _Pragma("unroll")                                                        \
        for (int i = 0; i < 4; ++i) {                                            \
            const int pix = wv * 16 + ((l >> 4) << 2) + i;                       \
            const int hw  = (h0 + (pix >> 5)) * WW + w0 + (pix & 31);            \
            float v = fmaf(ASsp, ACC[i], bias);                                  \
            float r = fmaxf(v, 0.f);                                             \
            float k = fminf(rintf(r * 32.f), 127.f);                             \
            ob[(size_t)o * HW + hw] = k * FS_;                                   \
        }                                                                        }
    PEPI(pc0, 0) PEPI(pc1, 1) PEPI(pc2, 2) PEPI(pc3, 3) PEPI(pc4, 4)
#undef PEPI

    if (tid < 128) {
        const int ch  = tid >> 6;
        const int pix = tid & 63;
        const int hw  = (h0 + (pix >> 5)) * WW + w0 + (pix & 31);
        const float f = flow[(size_t)(b * 2 + ch) * HW + hw];
        const float k = clip127(rintf(f * 32.f));
        ob[(size_t)(80 + ch) * HW + hw] = k * FS_;
    }
}

// ---------------- launcher ----------------
extern "C" void kernel_launch(void* const* d_in, const int* in_sizes, int n_in,
                              void* d_out, int out_size, void* d_ws, size_t ws_size,
                              hipStream_t stream) {
    const float* flow = (const float*)d_in[0];
    const float* corr = (const float*)d_in[1];
    const float* Wc1  = (const float*)d_in[2];
    const float* bc1  = (const float*)d_in[3];
    const float* Wf1  = (const float*)d_in[4];
    const float* bf1  = (const float*)d_in[5];
    const float* Wf2  = (const float*)d_in[6];
    const float* bf2  = (const float*)d_in[7];
    const float* Wd   = (const float*)d_in[8];
    const float* bd   = (const float*)d_in[9];
    const float* Wp   = (const float*)d_in[10];
    const float* bp   = (const float*)d_in[11];

    float* ws = (float*)d_ws;
    signed char* cfq = (signed char*)d_ws + CFQ_BYTE_OFF;
    float* out = (float*)d_out;

    quant_weights<<<5, 256, 0, stream>>>(Wc1, Wf1, Wf2, Wd, Wp, ws);
    k1_convc1<<<NPIX / 64, 256, 0, stream>>>(corr, bc1, ws, cfq);
    k1_flo<<<NPIX / 256, 256, 0, stream>>>(flow, bf1, bf2, ws, cfq);
    k2_dwpw<<<2400, 256, 0, stream>>>(flow, bd, bp, ws, cfq, out);
}